// Round 1
// baseline (178.507 us; speedup 1.0000x reference)
//
#include <hip/hip_runtime.h>

typedef unsigned short u16;
typedef __attribute__((ext_vector_type(8))) short short8;
typedef __attribute__((ext_vector_type(4))) float f32x4;

#define NGK 256
#define X0  (-6.0f)
#define GH  (12.0f / 256.0f)   // grid spacing h = 0.046875

__device__ __forceinline__ u16 f2bf(float x) {
    union { float f; unsigned int u; } v; v.f = x;
    unsigned int r = (v.u + 0x7fffu + ((v.u >> 16) & 1u)) >> 16;
    return (u16)r;
}
__device__ __forceinline__ unsigned int pk(u16 a, u16 b) {
    return (unsigned int)a | ((unsigned int)b << 16);
}

// blocks [0,256):  CIC-bin keys -> H[b][v][jk] bf16  (B^T layout, K-contiguous)
// blocks [256,512): Gq[b][t][jk] = exp(-0.5*(q_t - x_jk)^2 * invvar) bf16
__global__ __launch_bounds__(256) void prep_kernel(
    const float* __restrict__ query, const float* __restrict__ key,
    const float* __restrict__ value, const float* __restrict__ log_scale,
    u16* __restrict__ H, u16* __restrict__ Gq)
{
    __shared__ int   jj[4096];
    __shared__ float ff[4096];
    __shared__ float Hl[NGK * 9];   // [256 bins][8 v] padded stride 9 (bank spread)

    const int tid = threadIdx.x;
    const float ls = log_scale[0];
    const float invvar = exp2f(-2.0f * 1.44269504089f * ls);  // exp(-2*ls)
    const float c2 = -0.5f * 1.44269504089f * invvar;         // exp(c2'*d^2) via exp2

    if (blockIdx.x < 256) {
        const int b  = blockIdx.x >> 6;          // batch
        const int v0 = (blockIdx.x & 63) << 3;   // 8-row v slice (exclusive)
        for (int i = tid; i < NGK * 9; i += 256) Hl[i] = 0.0f;
        const float inv_h = 1.0f / GH;
        for (int r = 0; r < 16; ++r) {           // key -> (bin, frac) LUT
            int s = tid + (r << 8);
            float k = key[b * 4096 + s];
            float u = (k - X0) * inv_h;
            int j = (int)floorf(u);
            j = j < 0 ? 0 : (j > 254 ? 254 : j);
            float f = u - (float)j;
            f = f < 0.0f ? 0.0f : (f > 1.0f ? 1.0f : f);
            jj[s] = j; ff[s] = f;
        }
        __syncthreads();
        const int vloc  = tid >> 5;              // 0..7
        const int slane = tid & 31;
        const float* vrow = value + (size_t)(b * 512 + v0 + vloc) * 4096;
        for (int c = 0; c < 32; ++c) {           // coalesced: 32 lanes cover 512B/row
            int s = (slane << 2) + (c << 7);
            float4 val = *(const float4*)(vrow + s);
            int4   j4  = *(const int4*)(&jj[s]);
            float4 f4  = *(const float4*)(&ff[s]);
            atomicAdd(&Hl[ j4.x      * 9 + vloc], val.x * (1.0f - f4.x));
            atomicAdd(&Hl[(j4.x + 1) * 9 + vloc], val.x * f4.x);
            atomicAdd(&Hl[ j4.y      * 9 + vloc], val.y * (1.0f - f4.y));
            atomicAdd(&Hl[(j4.y + 1) * 9 + vloc], val.y * f4.y);
            atomicAdd(&Hl[ j4.z      * 9 + vloc], val.z * (1.0f - f4.z));
            atomicAdd(&Hl[(j4.z + 1) * 9 + vloc], val.z * f4.z);
            atomicAdd(&Hl[ j4.w      * 9 + vloc], val.w * (1.0f - f4.w));
            atomicAdd(&Hl[(j4.w + 1) * 9 + vloc], val.w * f4.w);
        }
        __syncthreads();
        const int jk0 = (slane) << 3;            // 32 jk-octets x 8 v = 256 threads
        u16 e[8];
        for (int r = 0; r < 8; ++r) e[r] = f2bf(Hl[(jk0 + r) * 9 + vloc]);
        uint4 ov = make_uint4(pk(e[0],e[1]), pk(e[2],e[3]), pk(e[4],e[5]), pk(e[6],e[7]));
        *(uint4*)(H + (size_t)(b * 512 + v0 + vloc) * 256 + jk0) = ov;
    } else {
        const int idx = blockIdx.x - 256;        // 0..255
        const int b = idx >> 6;
        const int t = ((idx & 63) << 6) + (tid >> 2);
        const int q4 = (tid & 3) << 6;           // 64-jk quarter
        const float q = query[b * 4096 + t];
        u16* orow = Gq + (size_t)(b * 4096 + t) * 256 + q4;
        for (int i0 = 0; i0 < 64; i0 += 8) {
            u16 e[8];
            for (int i = 0; i < 8; ++i) {
                float x = X0 + GH * (float)(q4 + i0 + i);
                float d = q - x;
                e[i] = f2bf(exp2f(c2 * d * d));
            }
            uint4 ov = make_uint4(pk(e[0],e[1]), pk(e[2],e[3]), pk(e[4],e[5]), pk(e[6],e[7]));
            *(uint4*)(orow + i0) = ov;
        }
    }
}

// out[b][t][v] = sum_jk Gq[b][t][jk] * H[b][v][jk]
// M=4096(t) N=512(v) K=256(jk), 128x128 tile, mfma_f32_16x16x32_bf16
__global__ __launch_bounds__(256) void gemm_kernel(
    const u16* __restrict__ A,   // Gq [B*4096][256]
    const u16* __restrict__ Bm,  // H  [B*512][256]
    float* __restrict__ out)
{
    __shared__ u16 Al[128 * 40];   // row stride 40 shorts (80B): 2-way-max bank alias
    __shared__ u16 Bl[128 * 40];
    const int tid = threadIdx.x;
    const int v0 = blockIdx.x << 7;
    const int t0 = blockIdx.y << 7;
    const int b  = blockIdx.z;
    const int lane = tid & 63;
    const int wave = tid >> 6;
    const int wm = (wave & 1) << 6;
    const int wn = (wave >> 1) << 6;
    const int m15 = lane & 15;
    const int kq  = lane >> 4;       // quad 0..3

    f32x4 acc[4][4];
    for (int i = 0; i < 4; ++i)
        for (int j = 0; j < 4; ++j)
            acc[i][j] = (f32x4){0.f, 0.f, 0.f, 0.f};

    const int srow  = tid >> 1;          // 0..127
    const int spart = (tid & 1) << 4;    // 0 or 16 shorts (32B half-row)
    const u16* Ag = A  + (size_t)(b * 4096 + t0 + srow) * 256 + spart;
    const u16* Bg = Bm + (size_t)(b * 512  + v0 + srow) * 256 + spart;
    u16* Alw = Al + srow * 40 + spart;
    u16* Blw = Bl + srow * 40 + spart;

    for (int ks = 0; ks < 8; ++ks) {
        const int k0 = ks << 5;
        uint4 a0 = *(const uint4*)(Ag + k0);
        uint4 a1 = *(const uint4*)(Ag + k0 + 8);
        uint4 b0 = *(const uint4*)(Bg + k0);
        uint4 b1 = *(const uint4*)(Bg + k0 + 8);
        __syncthreads();
        *(uint4*)(Alw)     = a0;
        *(uint4*)(Alw + 8) = a1;
        *(uint4*)(Blw)     = b0;
        *(uint4*)(Blw + 8) = b1;
        __syncthreads();
        short8 af[4], bf[4];
        for (int i = 0; i < 4; ++i) {
            af[i] = *(const short8*)(Al + (wm + i * 16 + m15) * 40 + kq * 8);
            bf[i] = *(const short8*)(Bl + (wn + i * 16 + m15) * 40 + kq * 8);
        }
        for (int mi = 0; mi < 4; ++mi)
            for (int ni = 0; ni < 4; ++ni)
                acc[mi][ni] = __builtin_amdgcn_mfma_f32_16x16x32_bf16(
                    af[mi], bf[ni], acc[mi][ni], 0, 0, 0);
    }

    for (int mi = 0; mi < 4; ++mi) {
        for (int ni = 0; ni < 4; ++ni) {
            int v = v0 + wn + ni * 16 + m15;
            for (int r = 0; r < 4; ++r) {
                int t = t0 + wm + mi * 16 + (kq << 2) + r;   // row = quad*4 + reg
                out[(size_t)(b * 4096 + t) * 512 + v] = acc[mi][ni][r];
            }
        }
    }
}

extern "C" void kernel_launch(void* const* d_in, const int* in_sizes, int n_in,
                              void* d_out, int out_size, void* d_ws, size_t ws_size,
                              hipStream_t stream)
{
    const float* query = (const float*)d_in[0];   // [4,4096,1]
    const float* key   = (const float*)d_in[1];   // [4,4096,1]
    const float* value = (const float*)d_in[2];   // [4,512,4096]
    const float* lsc   = (const float*)d_in[3];   // scalar
    float* out = (float*)d_out;                   // [4,4096,512]
    u16* H  = (u16*)d_ws;                         // [4][512][256] bf16 = 1 MB
    u16* Gq = (u16*)d_ws + 524288;                // [4][4096][256] bf16 = 8 MB

    prep_kernel<<<512, 256, 0, stream>>>(query, key, value, lsc, H, Gq);
    gemm_kernel<<<dim3(4, 32, 4), 256, 0, stream>>>(Gq, H, out);
}